// Round 14
// baseline (1941.187 us; speedup 1.0000x reference)
//
#include <hip/hip_runtime.h>
#include <cstddef>

namespace {

typedef _Float16 half_t;
typedef _Float16 half2_t __attribute__((ext_vector_type(2)));
typedef _Float16 f16x4 __attribute__((ext_vector_type(4)));
typedef _Float16 f16x8 __attribute__((ext_vector_type(8)));
typedef float f32x4 __attribute__((ext_vector_type(4)));

constexpr int NB = 256;  // batch
constexpr int NT = 512;  // time
constexpr int NH = 128;  // hidden
constexpr int NG = 512;  // 4*NH gates

__device__ __forceinline__ float sigm(float x) { return 1.0f / (1.0f + __expf(-x)); }
__device__ __forceinline__ float tanh_(float x) { return 2.0f / (1.0f + __expf(-2.0f * x)) - 1.0f; }
__device__ __forceinline__ float dot4(float4 w, float4 v, float acc) {
  return fmaf(w.x, v.x, fmaf(w.y, v.y, fmaf(w.z, v.z, fmaf(w.w, v.w, acc))));
}
__device__ __forceinline__ float fdot2(half2_t a, half2_t b, float c) {
  return __builtin_amdgcn_fdot2(a, b, c, false);  // v_dot2_f32_f16, f32 accum
}
__device__ __forceinline__ void pinv8(f16x8& x) { asm volatile("" : "+v"(x)); }

// quad (4-lane) sum via DPP quad_perm -- VALU, not LDS pipe.
__device__ __forceinline__ float qreduce(float v) {
  int t = __builtin_amdgcn_update_dpp(0, __float_as_int(v), 0xB1, 0xF, 0xF, true);  // [1,0,3,2]
  v += __int_as_float(t);
  t = __builtin_amdgcn_update_dpp(0, __float_as_int(v), 0x4E, 0xF, 0xF, true);      // [2,3,0,1]
  return v + __int_as_float(t);
}

// fp32 -> fp16 conversion (weight prep)
__global__ void cvt_kernel(const float* __restrict__ s, half_t* __restrict__ d, int n4) {
  int i = blockIdx.x * blockDim.x + threadIdx.x;
  if (i < n4) {
    float4 v = reinterpret_cast<const float4*>(s)[i];
    f16x4 hv = {(half_t)v.x, (half_t)v.y, (half_t)v.z, (half_t)v.w};
    reinterpret_cast<f16x4*>(d)[i] = hv;
  }
}

// ============ MFMA GEMM: C = A[M,K] * B[N,K]^T + biases ============  (r10, validated)
// !F32OUT: B rows permuted at load (orig = (n&3)*128 + (n>>2)) -> unit-interleaved
//          xg output Ch[m*NG+n], PRE-SCALED by 0.25 (quad-sum in rec restores).
// F32OUT : projection Cf[m*Nstr+n], unscaled.
template <int K, bool AF32, bool F32OUT>
__global__ __launch_bounds__(256) void xg_gemm(
    const void* __restrict__ Ap, const float* __restrict__ Bw,
    const float* __restrict__ b0, const float* __restrict__ b1,
    half_t* __restrict__ Ch, float* __restrict__ Cf, int Nstr)
{
  __shared__ __align__(16) half_t Atile[128 * K];
  __shared__ __align__(16) half_t Btile[64 * K];
  const int tid = threadIdx.x;
  const int m0 = blockIdx.x * 128;
  const int n0 = blockIdx.y * 64;
  char* Ab = (char*)Atile;
  char* Bb = (char*)Btile;

  if (AF32) {
    const float* Af = (const float*)Ap;
    for (int idx = tid; idx < 128 * K / 4; idx += 256) {
      int row = idx / (K / 4), o = idx % (K / 4);
      float4 v = *(const float4*)(Af + (size_t)(m0 + row) * K + 4 * o);
      f16x4 hv = {(half_t)v.x, (half_t)v.y, (half_t)v.z, (half_t)v.w};
      int byte = ((row * K + 4 * o) * 2) ^ ((row & 7) << 4);
      *(f16x4*)(Ab + byte) = hv;
    }
  } else {
    const half_t* Ah = (const half_t*)Ap;
    for (int idx = tid; idx < 128 * K / 8; idx += 256) {
      int row = idx / (K / 8), o = idx % (K / 8);
      uint4 v = *(const uint4*)(Ah + (size_t)(m0 + row) * K + 8 * o);
      int byte = ((row * K + 8 * o) * 2) ^ ((row & 7) << 4);
      *(uint4*)(Ab + byte) = v;
    }
  }
  for (int idx = tid; idx < 64 * K / 4; idx += 256) {
    int row = idx / (K / 4), o = idx % (K / 4);
    int n = n0 + row;
    int src_row = F32OUT ? n : ((n & 3) * 128 + (n >> 2));  // gate-interleave permutation
    float4 v = *(const float4*)(Bw + (size_t)src_row * K + 4 * o);
    f16x4 hv = {(half_t)v.x, (half_t)v.y, (half_t)v.z, (half_t)v.w};
    int byte = ((row * K + 4 * o) * 2) ^ ((row & 7) << 4);
    *(f16x4*)(Bb + byte) = hv;
  }
  __syncthreads();

  const int lane = tid & 63, w = tid >> 6;
  const int r16 = lane & 15, koff = (lane >> 4) * 8;
  f32x4 acc[2][4];
#pragma unroll
  for (int fm = 0; fm < 2; ++fm)
#pragma unroll
    for (int fn = 0; fn < 4; ++fn) acc[fm][fn] = (f32x4){0.f, 0.f, 0.f, 0.f};

#pragma unroll
  for (int ks = 0; ks < K / 32; ++ks) {
    f16x8 a[2], bf[4];
#pragma unroll
    for (int fm = 0; fm < 2; ++fm) {
      int row = w * 32 + fm * 16 + r16;
      int byte = ((row * K + ks * 32 + koff) * 2) ^ ((row & 7) << 4);
      a[fm] = *(const f16x8*)(Ab + byte);
    }
#pragma unroll
    for (int fn = 0; fn < 4; ++fn) {
      int row = fn * 16 + r16;
      int byte = ((row * K + ks * 32 + koff) * 2) ^ ((row & 7) << 4);
      bf[fn] = *(const f16x8*)(Bb + byte);
    }
#pragma unroll
    for (int fm = 0; fm < 2; ++fm)
#pragma unroll
      for (int fn = 0; fn < 4; ++fn)
        acc[fm][fn] = __builtin_amdgcn_mfma_f32_16x16x32_f16(a[fm], bf[fn], acc[fm][fn], 0, 0, 0);
  }

#pragma unroll
  for (int fm = 0; fm < 2; ++fm)
#pragma unroll
    for (int fn = 0; fn < 4; ++fn) {
      int n = n0 + fn * 16 + r16;
      int bidx = F32OUT ? n : ((n & 3) * 128 + (n >> 2));
      float bb = (b0 ? b0[bidx] : 0.f) + (b1 ? b1[bidx] : 0.f);
#pragma unroll
      for (int q = 0; q < 4; ++q) {
        int m = m0 + w * 32 + fm * 16 + (lane >> 4) * 4 + q;
        float val = acc[fm][fn][q] + bb;
        if (F32OUT) Cf[(size_t)m * Nstr + n] = val;
        else        Ch[(size_t)m * NG + n] = (half_t)(val * 0.25f);  // pre-scaled for quad-sum
      }
    }
}

// ============ Fused 2-layer recurrent kernel (pipelined) ============
// 256 blocks x 512 threads (8 waves = 2/SIMD), 1 batch/block, j=tid>>2, kq=tid&3.
// Super-step s: L0 computes h0(s) [s<NT]; L1 computes h1(s-1) from
// concat[h1(s-2); h0(s-1)] [s>=1]. One barrier per super-step.
// r14 change: ALL of the super-step's LDS reads (L0's 4 + L1's 8 ds_read_b128)
// are issued at region entry -- every operand was made visible by the PREVIOUS
// barrier, so the LDS pipe runs under L0's VALU block instead of sitting on
// L1's critical path mid-step (G7).
template <bool DEC>
__global__ __attribute__((amdgpu_flat_work_group_size(512, 512)))
__attribute__((amdgpu_waves_per_eu(2, 2))) void rec_fused(
    const half_t* __restrict__ xg0,    // [NB*NT][NG] unit-interleaved, /4-scaled (enc)
    const float* __restrict__ hT_in,   // [NB,NH]   (dec)
    const float* __restrict__ Wih0_32, // [NG,NH] fp32 (dec: d0Wih)
    const float* __restrict__ b0a, const float* __restrict__ b0b,  // L0 biases (dec)
    const half_t* __restrict__ Whh0,   // [NG,NH] fp16
    const half_t* __restrict__ WhhC,   // [NG,NH] fp16 (L1 recurrent)
    const half_t* __restrict__ WihC,   // [NG,NH] fp16 (L1 input)
    const float* __restrict__ b1a, const float* __restrict__ b1b,  // L1 biases
    half_t* __restrict__ seq_out,      // [NB*NT][NH] (dec)
    float* __restrict__ hT_out)        // [NB,NH]     (enc)
{
  const int b = blockIdx.x;
  const int tid = threadIdx.x;
  const int j = tid >> 2;
  const int kq = tid & 3;

  // quarters padded to 48 halfs (96 B): bases on banks {0,24,16,8} per parity.
  __shared__ __align__(16) half_t h0buf[2][4][48];
  __shared__ __align__(16) half_t h1buf[2][4][48];
  __shared__ float xgc[NG];   // dec const-xg scratch
  __shared__ float hinf[NH];

  // L0 recurrent weights: 16 x f16x8 = 64 VGPRs, pinned.
  f16x8 wh0[4][4];
#pragma unroll
  for (int gi = 0; gi < 4; ++gi) {
    const f16x8* p = reinterpret_cast<const f16x8*>(Whh0 + (size_t)(gi * NH + j) * NH + kq * 32);
#pragma unroll
    for (int r = 0; r < 4; ++r) wh0[gi][r] = p[r];
  }
#pragma unroll
  for (int gi = 0; gi < 4; ++gi)
#pragma unroll
    for (int r = 0; r < 4; ++r) pinv8(wh0[gi][r]);

  // L1 concat weights: kq<2 -> WhhC (h1 dims), kq>=2 -> WihC (h0 dims);
  // cols (kq&1)*64..+64. 32 x f16x8 = 128 VGPRs, pinned.
  f16x8 wc[4][8];
  const half_t* cbase = (kq < 2) ? WhhC : WihC;
#pragma unroll
  for (int gi = 0; gi < 4; ++gi) {
    const f16x8* p =
        reinterpret_cast<const f16x8*>(cbase + (size_t)(gi * NH + j) * NH + (kq & 1) * 64);
#pragma unroll
    for (int r = 0; r < 8; ++r) wc[gi][r] = p[r];
  }
#pragma unroll
  for (int gi = 0; gi < 4; ++gi)
#pragma unroll
    for (int r = 0; r < 8; ++r) pinv8(wc[gi][r]);

  float b1g[4];  // L1 bias, /4-folded (quad-sum restores)
#pragma unroll
  for (int gi = 0; gi < 4; ++gi)
    b1g[gi] = (b1a[gi * NH + j] + b1b[gi * NH + j]) * 0.25f;

  if (tid < NH) {  // h0(-1)=0 (parity 1), h1(-1)=0 (parity 1)
    h0buf[1][tid >> 5][tid & 31] = (half_t)0.f;
    h1buf[1][tid >> 5][tid & 31] = (half_t)0.f;
  }

  float c0 = 0.f, c1 = 0.f;
  float cx[4] = {0.f, 0.f, 0.f, 0.f};  // dec L0 const xg, /4-folded

  if (DEC) {
    if (tid < NH) hinf[tid] = hT_in[(size_t)b * NH + tid];
    __syncthreads();
    float a0 = b0a[tid] + b0b[tid], a1 = 0.f, a2 = 0.f, a3 = 0.f;
    const float4* wr = (const float4*)(Wih0_32 + (size_t)tid * NH);
    const float4* hv = (const float4*)hinf;
#pragma unroll
    for (int k = 0; k < 8; ++k) {
      a0 = dot4(wr[4 * k + 0], hv[4 * k + 0], a0);
      a1 = dot4(wr[4 * k + 1], hv[4 * k + 1], a1);
      a2 = dot4(wr[4 * k + 2], hv[4 * k + 2], a2);
      a3 = dot4(wr[4 * k + 3], hv[4 * k + 3], a3);
    }
    xgc[tid] = (a0 + a1) + (a2 + a3);
    __syncthreads();
    cx[0] = xgc[j] * 0.25f;       cx[1] = xgc[j + 128] * 0.25f;
    cx[2] = xgc[j + 256] * 0.25f; cx[3] = xgc[j + 384] * 0.25f;
  }

  // enc L0 xg prefetch, depth 2 (named regs)
  const half_t* xbase = nullptr;
  f16x4 xqA = {}, xqB = {};
  if (!DEC) {
    xbase = xg0 + (size_t)b * NT * NG + (j << 2);
    xqA = *(const f16x4*)(xbase);
    xqB = *(const f16x4*)(xbase + NG);
  }

  __syncthreads();

  auto stepf = [&](int s, f16x4& xq) {
    // ---- early-issue ALL LDS reads for this super-step (operands were made
    // visible by the previous barrier; LDS latency hides under L0's VALU) ----
    f16x8 hA[4];           // L0: h0(s-1), quarter kq
    if (s < NT) {
      const f16x8* hv8 = reinterpret_cast<const f16x8*>(&h0buf[(s + 1) & 1][kq][0]);
#pragma unroll
      for (int r8 = 0; r8 < 4; ++r8) hA[r8] = hv8[r8];
    }
    f16x8 HA[4], HB[4];    // L1: concat [h1(s-2); h0(s-1)], this thread's halves
    if (s >= 1) {
      const half_t* cA = (kq < 2) ? &h1buf[s & 1][2 * (kq & 1)][0]
                                  : &h0buf[(s + 1) & 1][2 * (kq & 1)][0];
      const f16x8* A8 = reinterpret_cast<const f16x8*>(cA);
      const f16x8* B8 = reinterpret_cast<const f16x8*>(cA + 48);  // next quarter
#pragma unroll
      for (int r8 = 0; r8 < 4; ++r8) { HA[r8] = A8[r8]; HB[r8] = B8[r8]; }
    }

    // ---------- L0: t = s ----------
    if (s < NT) {
      f16x4 cur = xq;
      if (!DEC && s + 2 < NT)
        xq = *(const f16x4*)(xbase + (size_t)(s + 2) * NG);  // issue early

      float pa[4], pb[4];
      if (DEC) {
#pragma unroll
        for (int gi = 0; gi < 4; ++gi) pa[gi] = cx[gi];
      } else {
#pragma unroll
        for (int gi = 0; gi < 4; ++gi) pa[gi] = (float)cur[gi];  // GEMM pre-scaled by 1/4
      }
#pragma unroll
      for (int gi = 0; gi < 4; ++gi) pb[gi] = 0.f;

#pragma unroll
      for (int r8 = 0; r8 < 4; ++r8) {
        const f16x8 H = hA[r8];
        const half2_t h0 = __builtin_shufflevector(H, H, 0, 1);
        const half2_t h1 = __builtin_shufflevector(H, H, 2, 3);
        const half2_t h2 = __builtin_shufflevector(H, H, 4, 5);
        const half2_t h3 = __builtin_shufflevector(H, H, 6, 7);
#pragma unroll
        for (int gi = 0; gi < 4; ++gi) {
          const f16x8 W = wh0[gi][r8];
          float sa = pa[gi], sb = pb[gi];
          sa = fdot2(__builtin_shufflevector(W, W, 0, 1), h0, sa);
          sb = fdot2(__builtin_shufflevector(W, W, 2, 3), h1, sb);
          sa = fdot2(__builtin_shufflevector(W, W, 4, 5), h2, sa);
          sb = fdot2(__builtin_shufflevector(W, W, 6, 7), h3, sb);
          pa[gi] = sa; pb[gi] = sb;
        }
      }
      const float a0 = qreduce(pa[0] + pb[0]);
      const float a1 = qreduce(pa[1] + pb[1]);
      const float a2 = qreduce(pa[2] + pb[2]);
      const float a3 = qreduce(pa[3] + pb[3]);

      const float ig = sigm(a0), fg = sigm(a1), gg = tanh_(a2), og = sigm(a3);
      c0 = fmaf(fg, c0, ig * gg);
      const float hh0 = og * tanh_(c0);
      if (kq == 0) h0buf[s & 1][j >> 5][j & 31] = (half_t)hh0;
    }

    // ---------- L1: t1 = s-1, concat [h1(s-2); h0(s-1)] (preloaded) ----------
    if (s >= 1) {
      float pc[4], pd[4];
#pragma unroll
      for (int gi = 0; gi < 4; ++gi) { pc[gi] = b1g[gi]; pd[gi] = 0.f; }

#pragma unroll
      for (int r8 = 0; r8 < 4; ++r8) {
        const f16x8 HAv = HA[r8];
        const f16x8 HBv = HB[r8];
        const half2_t a0p = __builtin_shufflevector(HAv, HAv, 0, 1);
        const half2_t a1p = __builtin_shufflevector(HAv, HAv, 2, 3);
        const half2_t a2p = __builtin_shufflevector(HAv, HAv, 4, 5);
        const half2_t a3p = __builtin_shufflevector(HAv, HAv, 6, 7);
        const half2_t b0p = __builtin_shufflevector(HBv, HBv, 0, 1);
        const half2_t b1p = __builtin_shufflevector(HBv, HBv, 2, 3);
        const half2_t b2p = __builtin_shufflevector(HBv, HBv, 4, 5);
        const half2_t b3p = __builtin_shufflevector(HBv, HBv, 6, 7);
#pragma unroll
        for (int gi = 0; gi < 4; ++gi) {
          const f16x8 WA = wc[gi][r8];
          const f16x8 WB = wc[gi][r8 + 4];
          float sc = pc[gi], sd = pd[gi];
          sc = fdot2(__builtin_shufflevector(WA, WA, 0, 1), a0p, sc);
          sd = fdot2(__builtin_shufflevector(WB, WB, 0, 1), b0p, sd);
          sc = fdot2(__builtin_shufflevector(WA, WA, 2, 3), a1p, sc);
          sd = fdot2(__builtin_shufflevector(WB, WB, 2, 3), b1p, sd);
          sc = fdot2(__builtin_shufflevector(WA, WA, 4, 5), a2p, sc);
          sd = fdot2(__builtin_shufflevector(WB, WB, 4, 5), b2p, sd);
          sc = fdot2(__builtin_shufflevector(WA, WA, 6, 7), a3p, sc);
          sd = fdot2(__builtin_shufflevector(WB, WB, 6, 7), b3p, sd);
          pc[gi] = sc; pd[gi] = sd;
        }
      }
      const float a0 = qreduce(pc[0] + pd[0]);
      const float a1 = qreduce(pc[1] + pd[1]);
      const float a2 = qreduce(pc[2] + pd[2]);
      const float a3 = qreduce(pc[3] + pd[3]);

      const float ig = sigm(a0), fg = sigm(a1), gg = tanh_(a2), og = sigm(a3);
      c1 = fmaf(fg, c1, ig * gg);
      const float hh1 = og * tanh_(c1);

      if (kq == 0) {
        h1buf[(s + 1) & 1][j >> 5][j & 31] = (half_t)hh1;
        if (DEC) seq_out[((size_t)b * NT + (s - 1)) * NH + j] = (half_t)hh1;
        else if (s == NT) hT_out[(size_t)b * NH + j] = hh1;
      }
    }
    __syncthreads();
  };

#pragma unroll 1
  for (int s = 0; s < NT; s += 2) {
    stepf(s, xqA);
    stepf(s + 1, xqB);
  }
  stepf(NT, xqA);  // drain: L1 computes t1 = NT-1 (L0 guarded off)
}

}  // namespace

extern "C" void kernel_launch(void* const* d_in, const int* in_sizes, int n_in,
                              void* d_out, int out_size, void* d_ws, size_t ws_size,
                              hipStream_t stream) {
  (void)in_sizes; (void)n_in; (void)out_size; (void)ws_size;

  const float* x     = (const float*)d_in[0];
  const float* e0Wih = (const float*)d_in[1];
  const float* e0Whh = (const float*)d_in[2];
  const float* e0bih = (const float*)d_in[3];
  const float* e0bhh = (const float*)d_in[4];
  const float* e1Wih = (const float*)d_in[5];
  const float* e1Whh = (const float*)d_in[6];
  const float* e1bih = (const float*)d_in[7];
  const float* e1bhh = (const float*)d_in[8];
  const float* d0Wih = (const float*)d_in[9];
  const float* d0Whh = (const float*)d_in[10];
  const float* d0bih = (const float*)d_in[11];
  const float* d0bhh = (const float*)d_in[12];
  const float* d1Wih = (const float*)d_in[13];
  const float* d1Whh = (const float*)d_in[14];
  const float* d1bih = (const float*)d_in[15];
  const float* d1bhh = (const float*)d_in[16];
  const float* Wout  = (const float*)d_in[17];
  const float* bout  = (const float*)d_in[18];
  float* out = (float*)d_out;

  // ws: 6 fp16 weight arrays | seqA fp16 [B*T,128] | xg0 fp16 [B*T,512] | hT f32
  half_t* whh0h = (half_t*)d_ws;
  half_t* whh1h = whh0h + 512 * 128;
  half_t* wih1h = whh1h + 512 * 128;
  half_t* whh2h = wih1h + 512 * 128;
  half_t* whh3h = whh2h + 512 * 128;
  half_t* wih3h = whh3h + 512 * 128;
  half_t* seqA  = wih3h + 512 * 128;
  half_t* xg0   = seqA + (size_t)NB * NT * NH;
  float*  hT    = (float*)(xg0 + (size_t)NB * NT * NG);

  cvt_kernel<<<64, 256, 0, stream>>>(e0Whh, whh0h, 512 * 128 / 4);
  cvt_kernel<<<64, 256, 0, stream>>>(e1Whh, whh1h, 512 * 128 / 4);
  cvt_kernel<<<64, 256, 0, stream>>>(e1Wih, wih1h, 512 * 128 / 4);
  cvt_kernel<<<64, 256, 0, stream>>>(d0Whh, whh2h, 512 * 128 / 4);
  cvt_kernel<<<64, 256, 0, stream>>>(d1Whh, whh3h, 512 * 128 / 4);
  cvt_kernel<<<64, 256, 0, stream>>>(d1Wih, wih3h, 512 * 128 / 4);

  const int M = NB * NT;  // 131072
  dim3 gX(M / 128, NG / 64), gP(M / 128, 1), blkG(256);
  dim3 gR(NB), blkR(512);

  // enc0 input GEMM: xg0 = (x @ e0Wih^T + biases)/4 (unit-interleaved)
  xg_gemm<64, true, false><<<gX, blkG, 0, stream>>>(x, e0Wih, e0bih, e0bhh, xg0, nullptr, NG);

  // fused encoder (enc0 + enc1): xg0 -> hT
  rec_fused<false><<<gR, blkR, 0, stream>>>(xg0, nullptr, nullptr, nullptr, nullptr,
                                            whh0h, whh1h, wih1h, e1bih, e1bhh,
                                            nullptr, hT);

  // fused decoder (dec0 + dec1): hT -> seqA (dec1 h-seq)
  rec_fused<true><<<gR, blkR, 0, stream>>>(nullptr, hT, d0Wih, d0bih, d0bhh,
                                           whh2h, whh3h, wih3h, d1bih, d1bhh,
                                           seqA, nullptr);

  // projection: out[b][t][f] = seqA @ Wout^T + bout
  xg_gemm<128, false, true><<<gP, blkG, 0, stream>>>(seqA, Wout, bout, nullptr, nullptr, out, 64);
}

// Round 15
// 1802.653 us; speedup vs baseline: 1.0769x; 1.0769x over previous
//
#include <hip/hip_runtime.h>
#include <cstddef>

namespace {

typedef _Float16 half_t;
typedef _Float16 half2_t __attribute__((ext_vector_type(2)));
typedef _Float16 f16x4 __attribute__((ext_vector_type(4)));
typedef _Float16 f16x8 __attribute__((ext_vector_type(8)));
typedef float f32x4 __attribute__((ext_vector_type(4)));

constexpr int NB = 256;  // batch
constexpr int NT = 512;  // time
constexpr int NH = 128;  // hidden
constexpr int NG = 512;  // 4*NH gates

#if __has_attribute(amdgpu_agpr_alloc)
#define NO_AGPR __attribute__((amdgpu_agpr_alloc(0)))
#else
#define NO_AGPR
#endif

__device__ __forceinline__ float sigm(float x) { return 1.0f / (1.0f + __expf(-x)); }
__device__ __forceinline__ float tanh_(float x) { return 2.0f / (1.0f + __expf(-2.0f * x)) - 1.0f; }
__device__ __forceinline__ float dot4(float4 w, float4 v, float acc) {
  return fmaf(w.x, v.x, fmaf(w.y, v.y, fmaf(w.z, v.z, fmaf(w.w, v.w, acc))));
}
__device__ __forceinline__ float fdot2(half2_t a, half2_t b, float c) {
  return __builtin_amdgcn_fdot2(a, b, c, false);  // v_dot2_f32_f16, f32 accum
}
__device__ __forceinline__ void pinv2(half2_t& x) { asm volatile("" : "+v"(x)); }

// quad (4-lane) sum via DPP quad_perm -- VALU, not LDS pipe.
__device__ __forceinline__ float qreduce(float v) {
  int t = __builtin_amdgcn_update_dpp(0, __float_as_int(v), 0xB1, 0xF, 0xF, true);  // [1,0,3,2]
  v += __int_as_float(t);
  t = __builtin_amdgcn_update_dpp(0, __float_as_int(v), 0x4E, 0xF, 0xF, true);      // [2,3,0,1]
  return v + __int_as_float(t);
}

// fp32 -> fp16 conversion (weight prep)
__global__ void cvt_kernel(const float* __restrict__ s, half_t* __restrict__ d, int n4) {
  int i = blockIdx.x * blockDim.x + threadIdx.x;
  if (i < n4) {
    float4 v = reinterpret_cast<const float4*>(s)[i];
    f16x4 hv = {(half_t)v.x, (half_t)v.y, (half_t)v.z, (half_t)v.w};
    reinterpret_cast<f16x4*>(d)[i] = hv;
  }
}

// ============ MFMA GEMM: C = A[M,K] * B[N,K]^T + biases ============  (r10, validated)
// !F32OUT: B rows permuted at load (orig = (n&3)*128 + (n>>2)) -> unit-interleaved
//          xg output Ch[m*NG+n], PRE-SCALED by 0.25 (quad-sum in rec restores).
// F32OUT : projection Cf[m*Nstr+n], unscaled.
template <int K, bool AF32, bool F32OUT>
__global__ __launch_bounds__(256) void xg_gemm(
    const void* __restrict__ Ap, const float* __restrict__ Bw,
    const float* __restrict__ b0, const float* __restrict__ b1,
    half_t* __restrict__ Ch, float* __restrict__ Cf, int Nstr)
{
  __shared__ __align__(16) half_t Atile[128 * K];
  __shared__ __align__(16) half_t Btile[64 * K];
  const int tid = threadIdx.x;
  const int m0 = blockIdx.x * 128;
  const int n0 = blockIdx.y * 64;
  char* Ab = (char*)Atile;
  char* Bb = (char*)Btile;

  if (AF32) {
    const float* Af = (const float*)Ap;
    for (int idx = tid; idx < 128 * K / 4; idx += 256) {
      int row = idx / (K / 4), o = idx % (K / 4);
      float4 v = *(const float4*)(Af + (size_t)(m0 + row) * K + 4 * o);
      f16x4 hv = {(half_t)v.x, (half_t)v.y, (half_t)v.z, (half_t)v.w};
      int byte = ((row * K + 4 * o) * 2) ^ ((row & 7) << 4);
      *(f16x4*)(Ab + byte) = hv;
    }
  } else {
    const half_t* Ah = (const half_t*)Ap;
    for (int idx = tid; idx < 128 * K / 8; idx += 256) {
      int row = idx / (K / 8), o = idx % (K / 8);
      uint4 v = *(const uint4*)(Ah + (size_t)(m0 + row) * K + 8 * o);
      int byte = ((row * K + 8 * o) * 2) ^ ((row & 7) << 4);
      *(uint4*)(Ab + byte) = v;
    }
  }
  for (int idx = tid; idx < 64 * K / 4; idx += 256) {
    int row = idx / (K / 4), o = idx % (K / 4);
    int n = n0 + row;
    int src_row = F32OUT ? n : ((n & 3) * 128 + (n >> 2));  // gate-interleave permutation
    float4 v = *(const float4*)(Bw + (size_t)src_row * K + 4 * o);
    f16x4 hv = {(half_t)v.x, (half_t)v.y, (half_t)v.z, (half_t)v.w};
    int byte = ((row * K + 4 * o) * 2) ^ ((row & 7) << 4);
    *(f16x4*)(Bb + byte) = hv;
  }
  __syncthreads();

  const int lane = tid & 63, w = tid >> 6;
  const int r16 = lane & 15, koff = (lane >> 4) * 8;
  f32x4 acc[2][4];
#pragma unroll
  for (int fm = 0; fm < 2; ++fm)
#pragma unroll
    for (int fn = 0; fn < 4; ++fn) acc[fm][fn] = (f32x4){0.f, 0.f, 0.f, 0.f};

#pragma unroll
  for (int ks = 0; ks < K / 32; ++ks) {
    f16x8 a[2], bf[4];
#pragma unroll
    for (int fm = 0; fm < 2; ++fm) {
      int row = w * 32 + fm * 16 + r16;
      int byte = ((row * K + ks * 32 + koff) * 2) ^ ((row & 7) << 4);
      a[fm] = *(const f16x8*)(Ab + byte);
    }
#pragma unroll
    for (int fn = 0; fn < 4; ++fn) {
      int row = fn * 16 + r16;
      int byte = ((row * K + ks * 32 + koff) * 2) ^ ((row & 7) << 4);
      bf[fn] = *(const f16x8*)(Bb + byte);
    }
#pragma unroll
    for (int fm = 0; fm < 2; ++fm)
#pragma unroll
      for (int fn = 0; fn < 4; ++fn)
        acc[fm][fn] = __builtin_amdgcn_mfma_f32_16x16x32_f16(a[fm], bf[fn], acc[fm][fn], 0, 0, 0);
  }

#pragma unroll
  for (int fm = 0; fm < 2; ++fm)
#pragma unroll
    for (int fn = 0; fn < 4; ++fn) {
      int n = n0 + fn * 16 + r16;
      int bidx = F32OUT ? n : ((n & 3) * 128 + (n >> 2));
      float bb = (b0 ? b0[bidx] : 0.f) + (b1 ? b1[bidx] : 0.f);
#pragma unroll
      for (int q = 0; q < 4; ++q) {
        int m = m0 + w * 32 + fm * 16 + (lane >> 4) * 4 + q;
        float val = acc[fm][fn][q] + bb;
        if (F32OUT) Cf[(size_t)m * Nstr + n] = val;
        else        Ch[(size_t)m * NG + n] = (half_t)(val * 0.25f);  // pre-scaled for quad-sum
      }
    }
}

// ============ Fused 2-layer recurrent kernel (pipelined) ============
// 256 blocks x 512 threads (8 waves = 2/SIMD), 1 batch/block, j=tid>>2, kq=tid&3.
// Super-step s: L0 computes h0(s) [s<NT]; L1 computes h1(s-1) from
// concat[h1(s-2); h0(s-1)] [s>=1]. One barrier per super-step.
// r15 changes vs r11: (a) pinned weights held as individual half2_t registers
// (fdot2 consumes directly -- no f16x8 extract ops); (b) amdgpu_agpr_alloc(0)
// forbids AGPR allocation so the 192 pinned regs live in arch VGPRs without
// per-use v_accvgpr_read (r11: VGPR_Count=128 arch + shunt, ~192 extra
// VALU ops/step = the measured 3.4x VALU-cycle bloat).
template <bool DEC>
__global__ __attribute__((amdgpu_flat_work_group_size(512, 512)))
__attribute__((amdgpu_waves_per_eu(2, 2))) NO_AGPR void rec_fused(
    const half_t* __restrict__ xg0,    // [NB*NT][NG] unit-interleaved, /4-scaled (enc)
    const float* __restrict__ hT_in,   // [NB,NH]   (dec)
    const float* __restrict__ Wih0_32, // [NG,NH] fp32 (dec: d0Wih)
    const float* __restrict__ b0a, const float* __restrict__ b0b,  // L0 biases (dec)
    const half_t* __restrict__ Whh0,   // [NG,NH] fp16
    const half_t* __restrict__ WhhC,   // [NG,NH] fp16 (L1 recurrent)
    const half_t* __restrict__ WihC,   // [NG,NH] fp16 (L1 input)
    const float* __restrict__ b1a, const float* __restrict__ b1b,  // L1 biases
    half_t* __restrict__ seq_out,      // [NB*NT][NH] (dec)
    float* __restrict__ hT_out)        // [NB,NH]     (enc)
{
  const int b = blockIdx.x;
  const int tid = threadIdx.x;
  const int j = tid >> 2;
  const int kq = tid & 3;

  // quarters padded to 48 halfs (96 B): bases on banks {0,24,16,8} per parity.
  __shared__ __align__(16) half_t h0buf[2][4][48];
  __shared__ __align__(16) half_t h1buf[2][4][48];
  __shared__ float xgc[NG];   // dec const-xg scratch
  __shared__ float hinf[NH];

  // L0 recurrent weights: 64 individual half2_t (64 VGPRs), pinned.
  half2_t wh0[4][16];
#pragma unroll
  for (int gi = 0; gi < 4; ++gi) {
    const half2_t* p = reinterpret_cast<const half2_t*>(Whh0 + (size_t)(gi * NH + j) * NH + kq * 32);
#pragma unroll
    for (int r = 0; r < 16; ++r) wh0[gi][r] = p[r];
  }
#pragma unroll
  for (int gi = 0; gi < 4; ++gi)
#pragma unroll
    for (int r = 0; r < 16; ++r) pinv2(wh0[gi][r]);

  // L1 concat weights: kq<2 -> WhhC (h1 dims), kq>=2 -> WihC (h0 dims);
  // cols (kq&1)*64..+64 as 32 half2 per gate (first 16 = A-quarter cols 0..31,
  // last 16 = B-quarter cols 32..63). 128 half2 = 128 VGPRs, pinned.
  half2_t wc2[4][32];
  const half_t* cbase = (kq < 2) ? WhhC : WihC;
#pragma unroll
  for (int gi = 0; gi < 4; ++gi) {
    const half2_t* p =
        reinterpret_cast<const half2_t*>(cbase + (size_t)(gi * NH + j) * NH + (kq & 1) * 64);
#pragma unroll
    for (int r = 0; r < 32; ++r) wc2[gi][r] = p[r];
  }
#pragma unroll
  for (int gi = 0; gi < 4; ++gi)
#pragma unroll
    for (int r = 0; r < 32; ++r) pinv2(wc2[gi][r]);

  float b1g[4];  // L1 bias, /4-folded (quad-sum restores)
#pragma unroll
  for (int gi = 0; gi < 4; ++gi)
    b1g[gi] = (b1a[gi * NH + j] + b1b[gi * NH + j]) * 0.25f;

  if (tid < NH) {  // h0(-1)=0 (parity 1), h1(-1)=0 (parity 1)
    h0buf[1][tid >> 5][tid & 31] = (half_t)0.f;
    h1buf[1][tid >> 5][tid & 31] = (half_t)0.f;
  }

  float c0 = 0.f, c1 = 0.f;
  float cx[4] = {0.f, 0.f, 0.f, 0.f};  // dec L0 const xg, /4-folded

  if (DEC) {
    if (tid < NH) hinf[tid] = hT_in[(size_t)b * NH + tid];
    __syncthreads();
    float a0 = b0a[tid] + b0b[tid], a1 = 0.f, a2 = 0.f, a3 = 0.f;
    const float4* wr = (const float4*)(Wih0_32 + (size_t)tid * NH);
    const float4* hv = (const float4*)hinf;
#pragma unroll
    for (int k = 0; k < 8; ++k) {
      a0 = dot4(wr[4 * k + 0], hv[4 * k + 0], a0);
      a1 = dot4(wr[4 * k + 1], hv[4 * k + 1], a1);
      a2 = dot4(wr[4 * k + 2], hv[4 * k + 2], a2);
      a3 = dot4(wr[4 * k + 3], hv[4 * k + 3], a3);
    }
    xgc[tid] = (a0 + a1) + (a2 + a3);
    __syncthreads();
    cx[0] = xgc[j] * 0.25f;       cx[1] = xgc[j + 128] * 0.25f;
    cx[2] = xgc[j + 256] * 0.25f; cx[3] = xgc[j + 384] * 0.25f;
  }

  // enc L0 xg prefetch, depth 2 (named regs)
  const half_t* xbase = nullptr;
  f16x4 xqA = {}, xqB = {};
  if (!DEC) {
    xbase = xg0 + (size_t)b * NT * NG + (j << 2);
    xqA = *(const f16x4*)(xbase);
    xqB = *(const f16x4*)(xbase + NG);
  }

  __syncthreads();

  auto stepf = [&](int s, f16x4& xq) {
    // ---------- L0: t = s ----------
    if (s < NT) {
      f16x4 cur = xq;
      if (!DEC && s + 2 < NT)
        xq = *(const f16x4*)(xbase + (size_t)(s + 2) * NG);  // issue early

      float pa[4], pb[4];
      if (DEC) {
#pragma unroll
        for (int gi = 0; gi < 4; ++gi) pa[gi] = cx[gi];
      } else {
#pragma unroll
        for (int gi = 0; gi < 4; ++gi) pa[gi] = (float)cur[gi];  // GEMM pre-scaled by 1/4
      }
#pragma unroll
      for (int gi = 0; gi < 4; ++gi) pb[gi] = 0.f;

      const f16x8* hv8 = reinterpret_cast<const f16x8*>(&h0buf[(s + 1) & 1][kq][0]);
#pragma unroll
      for (int r8 = 0; r8 < 4; ++r8) {
        const f16x8 H = hv8[r8];
        const half2_t h0 = __builtin_shufflevector(H, H, 0, 1);
        const half2_t h1 = __builtin_shufflevector(H, H, 2, 3);
        const half2_t h2 = __builtin_shufflevector(H, H, 4, 5);
        const half2_t h3 = __builtin_shufflevector(H, H, 6, 7);
#pragma unroll
        for (int gi = 0; gi < 4; ++gi) {
          float sa = pa[gi], sb = pb[gi];
          sa = fdot2(wh0[gi][4 * r8 + 0], h0, sa);
          sb = fdot2(wh0[gi][4 * r8 + 1], h1, sb);
          sa = fdot2(wh0[gi][4 * r8 + 2], h2, sa);
          sb = fdot2(wh0[gi][4 * r8 + 3], h3, sb);
          pa[gi] = sa; pb[gi] = sb;
        }
      }
      const float a0 = qreduce(pa[0] + pb[0]);
      const float a1 = qreduce(pa[1] + pb[1]);
      const float a2 = qreduce(pa[2] + pb[2]);
      const float a3 = qreduce(pa[3] + pb[3]);

      const float ig = sigm(a0), fg = sigm(a1), gg = tanh_(a2), og = sigm(a3);
      c0 = fmaf(fg, c0, ig * gg);
      const float hh0 = og * tanh_(c0);
      if (kq == 0) h0buf[s & 1][j >> 5][j & 31] = (half_t)hh0;
    }

    // ---------- L1: t1 = s-1, concat [h1(s-2); h0(s-1)] ----------
    if (s >= 1) {
      const half_t* cA = (kq < 2) ? &h1buf[s & 1][2 * (kq & 1)][0]
                                  : &h0buf[(s + 1) & 1][2 * (kq & 1)][0];
      const f16x8* A8 = reinterpret_cast<const f16x8*>(cA);
      const f16x8* B8 = reinterpret_cast<const f16x8*>(cA + 48);  // next quarter

      float pc[4], pd[4];
#pragma unroll
      for (int gi = 0; gi < 4; ++gi) { pc[gi] = b1g[gi]; pd[gi] = 0.f; }

#pragma unroll
      for (int r8 = 0; r8 < 4; ++r8) {
        const f16x8 HAv = A8[r8];
        const f16x8 HBv = B8[r8];
        const half2_t a0p = __builtin_shufflevector(HAv, HAv, 0, 1);
        const half2_t a1p = __builtin_shufflevector(HAv, HAv, 2, 3);
        const half2_t a2p = __builtin_shufflevector(HAv, HAv, 4, 5);
        const half2_t a3p = __builtin_shufflevector(HAv, HAv, 6, 7);
        const half2_t b0p = __builtin_shufflevector(HBv, HBv, 0, 1);
        const half2_t b1p = __builtin_shufflevector(HBv, HBv, 2, 3);
        const half2_t b2p = __builtin_shufflevector(HBv, HBv, 4, 5);
        const half2_t b3p = __builtin_shufflevector(HBv, HBv, 6, 7);
#pragma unroll
        for (int gi = 0; gi < 4; ++gi) {
          float sc = pc[gi], sd = pd[gi];
          sc = fdot2(wc2[gi][4 * r8 + 0], a0p, sc);
          sd = fdot2(wc2[gi][16 + 4 * r8 + 0], b0p, sd);
          sc = fdot2(wc2[gi][4 * r8 + 1], a1p, sc);
          sd = fdot2(wc2[gi][16 + 4 * r8 + 1], b1p, sd);
          sc = fdot2(wc2[gi][4 * r8 + 2], a2p, sc);
          sd = fdot2(wc2[gi][16 + 4 * r8 + 2], b2p, sd);
          sc = fdot2(wc2[gi][4 * r8 + 3], a3p, sc);
          sd = fdot2(wc2[gi][16 + 4 * r8 + 3], b3p, sd);
          pc[gi] = sc; pd[gi] = sd;
        }
      }
      const float a0 = qreduce(pc[0] + pd[0]);
      const float a1 = qreduce(pc[1] + pd[1]);
      const float a2 = qreduce(pc[2] + pd[2]);
      const float a3 = qreduce(pc[3] + pd[3]);

      const float ig = sigm(a0), fg = sigm(a1), gg = tanh_(a2), og = sigm(a3);
      c1 = fmaf(fg, c1, ig * gg);
      const float hh1 = og * tanh_(c1);

      if (kq == 0) {
        h1buf[(s + 1) & 1][j >> 5][j & 31] = (half_t)hh1;
        if (DEC) seq_out[((size_t)b * NT + (s - 1)) * NH + j] = (half_t)hh1;
        else if (s == NT) hT_out[(size_t)b * NH + j] = hh1;
      }
    }
    __syncthreads();
  };

#pragma unroll 1
  for (int s = 0; s < NT; s += 2) {
    stepf(s, xqA);
    stepf(s + 1, xqB);
  }
  stepf(NT, xqA);  // drain: L1 computes t1 = NT-1 (L0 guarded off)
}

}  // namespace

extern "C" void kernel_launch(void* const* d_in, const int* in_sizes, int n_in,
                              void* d_out, int out_size, void* d_ws, size_t ws_size,
                              hipStream_t stream) {
  (void)in_sizes; (void)n_in; (void)out_size; (void)ws_size;

  const float* x     = (const float*)d_in[0];
  const float* e0Wih = (const float*)d_in[1];
  const float* e0Whh = (const float*)d_in[2];
  const float* e0bih = (const float*)d_in[3];
  const float* e0bhh = (const float*)d_in[4];
  const float* e1Wih = (const float*)d_in[5];
  const float* e1Whh = (const float*)d_in[6];
  const float* e1bih = (const float*)d_in[7];
  const float* e1bhh = (const float*)d_in[8];
  const float* d0Wih = (const float*)d_in[9];
  const float* d0Whh = (const float*)d_in[10];
  const float* d0bih = (const float*)d_in[11];
  const float* d0bhh = (const float*)d_in[12];
  const float* d1Wih = (const float*)d_in[13];
  const float* d1Whh = (const float*)d_in[14];
  const float* d1bih = (const float*)d_in[15];
  const float* d1bhh = (const float*)d_in[16];
  const float* Wout  = (const float*)d_in[17];
  const float* bout  = (const float*)d_in[18];
  float* out = (float*)d_out;

  // ws: 6 fp16 weight arrays | seqA fp16 [B*T,128] | xg0 fp16 [B*T,512] | hT f32
  half_t* whh0h = (half_t*)d_ws;
  half_t* whh1h = whh0h + 512 * 128;
  half_t* wih1h = whh1h + 512 * 128;
  half_t* whh2h = wih1h + 512 * 128;
  half_t* whh3h = whh2h + 512 * 128;
  half_t* wih3h = whh3h + 512 * 128;
  half_t* seqA  = wih3h + 512 * 128;
  half_t* xg0   = seqA + (size_t)NB * NT * NH;
  float*  hT    = (float*)(xg0 + (size_t)NB * NT * NG);

  cvt_kernel<<<64, 256, 0, stream>>>(e0Whh, whh0h, 512 * 128 / 4);
  cvt_kernel<<<64, 256, 0, stream>>>(e1Whh, whh1h, 512 * 128 / 4);
  cvt_kernel<<<64, 256, 0, stream>>>(e1Wih, wih1h, 512 * 128 / 4);
  cvt_kernel<<<64, 256, 0, stream>>>(d0Whh, whh2h, 512 * 128 / 4);
  cvt_kernel<<<64, 256, 0, stream>>>(d1Whh, whh3h, 512 * 128 / 4);
  cvt_kernel<<<64, 256, 0, stream>>>(d1Wih, wih3h, 512 * 128 / 4);

  const int M = NB * NT;  // 131072
  dim3 gX(M / 128, NG / 64), gP(M / 128, 1), blkG(256);
  dim3 gR(NB), blkR(512);

  // enc0 input GEMM: xg0 = (x @ e0Wih^T + biases)/4 (unit-interleaved)
  xg_gemm<64, true, false><<<gX, blkG, 0, stream>>>(x, e0Wih, e0bih, e0bhh, xg0, nullptr, NG);

  // fused encoder (enc0 + enc1): xg0 -> hT
  rec_fused<false><<<gR, blkR, 0, stream>>>(xg0, nullptr, nullptr, nullptr, nullptr,
                                            whh0h, whh1h, wih1h, e1bih, e1bhh,
                                            nullptr, hT);

  // fused decoder (dec0 + dec1): hT -> seqA (dec1 h-seq)
  rec_fused<true><<<gR, blkR, 0, stream>>>(nullptr, hT, d0Wih, d0bih, d0bhh,
                                           whh2h, whh3h, wih3h, d1bih, d1bhh,
                                           seqA, nullptr);

  // projection: out[b][t][f] = seqA @ Wout^T + bout
  xg_gemm<128, false, true><<<gP, blkG, 0, stream>>>(seqA, Wout, bout, nullptr, nullptr, out, 64);
}